// Round 1
// baseline (989.581 us; speedup 1.0000x reference)
//
#include <hip/hip_runtime.h>
#include <stdint.h>

#define T_LEN 4096
#define PAD   128
#define HROWS (T_LEN + 2*PAD)   // 4352 rows (zero pad 128 each side)
#define NCH   256
#define M2    512
#define BG    4
#define NL    8

using f4  = __attribute__((ext_vector_type(4))) float;
using bh8 = __attribute__((ext_vector_type(8))) short;
using s4v = __attribute__((ext_vector_type(4))) short;
using u4  = __attribute__((ext_vector_type(4))) unsigned int;

static __device__ __forceinline__ short f2b(float f){
  unsigned u = __builtin_bit_cast(unsigned, f);
  unsigned r = (u + 0x7FFFu + ((u >> 16) & 1u)) >> 16;
  return (short)r;
}
static __device__ __forceinline__ float b2f(short s){
  unsigned u = ((unsigned)(unsigned short)s) << 16;
  return __builtin_bit_cast(float, u);
}

#define MFMA(a,b,c) __builtin_amdgcn_mfma_f32_16x16x32_bf16((a),(b),(c),0,0,0)

// ---------------- prep: weights -> bf16, relayout ----------------
// W1[l][tap][o][c] = in_w[l][o][c][tap]
// W2[l][o][c]: l<7 -> rs_w[l][o][c]; l==7: o<256 -> 0 else rs_last_w[o-256][c]
// rsb8[l][o]:  l<7 -> rs_b[l][o];    l==7: o<256 -> 0 else rs_last_b[o-256]
__global__ void prep_w(const float* __restrict__ in_w, const float* __restrict__ rs_w,
                       const float* __restrict__ rs_last_w, const float* __restrict__ rs_b,
                       const float* __restrict__ rs_last_b,
                       short* __restrict__ W1, short* __restrict__ W2, float* __restrict__ rsb8){
  const int n1 = NL*3*M2*NCH;           // 3,145,728
  const int n2 = NL*M2*NCH;             // 1,048,576
  const int n3 = NL*M2;                 // 4,096
  for (int i = blockIdx.x*blockDim.x + threadIdx.x; i < n1+n2+n3; i += gridDim.x*blockDim.x){
    if (i < n1){
      int c = i & 255, o = (i >> 8) & 511, lt = i >> 17;
      int tap = lt % 3, l = lt / 3;
      W1[i] = f2b(in_w[(((l*M2 + o)*NCH + c)*3) + tap]);
    } else if (i < n1+n2){
      int j = i - n1;
      int c = j & 255, o = (j >> 8) & 511, l = j >> 17;
      float v;
      if (l < 7) v = rs_w[(l*M2 + o)*NCH + c];
      else       v = (o < NCH) ? 0.f : rs_last_w[(o-NCH)*NCH + c];
      W2[j] = f2b(v);
    } else {
      int k = i - n1 - n2;
      int o = k & 511, l = k >> 9;
      float v;
      if (l < 7) v = rs_b[l*M2 + o];
      else       v = (o < NCH) ? 0.f : rs_last_b[o-NCH];
      rsb8[k] = v;
    }
  }
}

// ---------------- prep: cb[b][ch] = in_b[ch] + pos_lin_b[ch] + pc[b][ch] ----------------
__global__ void prep_cb(const int* __restrict__ pos, const float* __restrict__ pos_emb_w,
                        const float* __restrict__ pos_lin_w, const float* __restrict__ pos_lin_b,
                        const float* __restrict__ in_b, float* __restrict__ cb){
  int b = blockIdx.y;
  int ch = blockIdx.x*blockDim.x + threadIdx.x;     // 0..4095
  int p = pos[b];
  float acc = pos_lin_b[ch] + in_b[ch];
  for (int k = 0; k < 128; ++k){
    float e = pos_emb_w[p*128 + k];
    e = e > 0.f ? e : 0.f;
    acc += e * pos_lin_w[ch*128 + k];
  }
  cb[b*4096 + ch] = acc;
}

// ---------------- prep: h0[b][t][c] (bf16, padded layout) ----------------
__global__ void prep_h0(const float* __restrict__ audio, const float* __restrict__ start_w,
                        const float* __restrict__ start_b, short* __restrict__ hA){
  __shared__ float sw[NCH*8];
  __shared__ float sb[NCH];
  int b = blockIdx.y, t0 = blockIdx.x*64;
  for (int i = threadIdx.x; i < NCH*8; i += 256) sw[i] = start_w[i];
  for (int i = threadIdx.x; i < NCH;   i += 256) sb[i] = start_b[i];
  __syncthreads();
  int t = t0 + (threadIdx.x & 63);
  int cg = threadIdx.x >> 6;
  float av[8];
  #pragma unroll
  for (int ic = 0; ic < 8; ++ic) av[ic] = audio[((size_t)(b*8 + ic))*T_LEN + t];
  short* dst = hA + ((size_t)b*HROWS + PAD + t)*NCH;
  for (int c = cg*64; c < cg*64 + 64; ++c){
    float acc = sb[c];
    #pragma unroll
    for (int ic = 0; ic < 8; ++ic) acc += sw[c*8 + ic]*av[ic];
    dst[c] = f2b(acc);
  }
}

// ---------------- prep: cond[ch][t] = cond_w @ spect + cond_b (bf16) ----------------
__global__ void cond_k(const float* __restrict__ spect, const float* __restrict__ cond_w,
                       const float* __restrict__ cond_b, short* __restrict__ cond){
  __shared__ float ssp[80*64];
  __shared__ float swt[32*80];
  int t0 = blockIdx.x*64, ch0 = blockIdx.y*32;
  for (int i = threadIdx.x; i < 80*64; i += 256){
    int c = i >> 6, t = i & 63;
    ssp[i] = spect[(size_t)c*T_LEN + t0 + t];
  }
  for (int i = threadIdx.x; i < 32*80; i += 256){
    int o = i / 80, k = i % 80;
    swt[i] = cond_w[(size_t)(ch0 + o)*80 + k];
  }
  __syncthreads();
  int t = threadIdx.x & 63, og = threadIdx.x >> 6;
  for (int j = 0; j < 8; ++j){
    int cl = og*8 + j;
    float acc = cond_b[ch0 + cl];
    for (int k = 0; k < 80; ++k) acc += swt[cl*80 + k]*ssp[(k << 6) + t];
    cond[(size_t)(ch0 + cl)*T_LEN + t0 + t] = f2b(acc);
  }
}

// ---------------- fused WaveNet layer ----------------
// grid (64 t-tiles, 4 batch), 512 threads (8 waves). 1 block/CU (128 KB LDS).
__global__ __launch_bounds__(512, 2) void wn_layer(
    const short* __restrict__ hSrc, short* __restrict__ hDst,
    const short* __restrict__ W1l, const short* __restrict__ W2l,
    const short* __restrict__ condl, const float* __restrict__ cb_l,
    const float* __restrict__ rsb_l, short* __restrict__ outb, int dil){

  __shared__ short Ht[3*64*NCH];   // 96 KB: 3 tap windows [64 t][256 c], XOR-swizzled
  __shared__ short xb[64*NCH];     // 32 KB: sigma exchange, then acts[t][c]

  const int tid  = threadIdx.x;
  const int w    = tid >> 6, lane = tid & 63;
  const int l15  = lane & 15, g = lane >> 4;
  const int tile = blockIdx.x, b = blockIdx.y;
  const int orow = w << 6;

  // ---- stage 3 h windows: global linear read -> swizzled LDS write ----
  {
    const int rsub = tid >> 5;            // 0..15
    const int innr = (tid & 31) << 3;     // short offset in row, 16B chunks
    #pragma unroll
    for (int tap = 0; tap < 3; ++tap){
      const int gbase = b*HROWS + PAD + tile*64 + (tap-1)*dil;
      #pragma unroll
      for (int ch = 0; ch < 4; ++ch){
        int r = ch*16 + rsub;
        u4 v = *(const u4*)(hSrc + (size_t)(gbase + r)*NCH + innr);
        *(u4*)(Ht + tap*16384 + r*NCH + (innr ^ ((r & 7) << 3))) = v;
      }
    }
  }
  __syncthreads();

  f4 acc[4][4];
  #pragma unroll
  for (int mf = 0; mf < 4; ++mf)
    #pragma unroll
    for (int nf = 0; nf < 4; ++nf) acc[mf][nf] = (f4){0.f,0.f,0.f,0.f};

  // ---- phase 1: dilated conv as 3 GEMMs, K=256 each ----
  #pragma unroll
  for (int tap = 0; tap < 3; ++tap){
    const short* Wt = W1l + ((size_t)(tap*M2 + orow))*NCH;
    #pragma unroll
    for (int kk = 0; kk < 8; ++kk){
      bh8 av[4], bv[4];
      #pragma unroll
      for (int mf = 0; mf < 4; ++mf)
        av[mf] = *(const bh8*)(Wt + (size_t)(mf*16 + l15)*NCH + kk*32 + g*8);
      #pragma unroll
      for (int nf = 0; nf < 4; ++nf){
        int t = nf*16 + l15;
        bv[nf] = *(const bh8*)(Ht + tap*16384 + t*NCH + ((kk*32 + g*8) ^ ((t & 7) << 3)));
      }
      #pragma unroll
      for (int mf = 0; mf < 4; ++mf)
        #pragma unroll
        for (int nf = 0; nf < 4; ++nf)
          acc[mf][nf] = MFMA(av[mf], bv[nf], acc[mf][nf]);
    }
  }

  // per-(mf,j) bias = cb (in_b + pos_lin_b + pc)
  float bias[4][4];
  #pragma unroll
  for (int mf = 0; mf < 4; ++mf){
    f4 t = *(const f4*)(cb_l + b*4096 + orow + mf*16 + 4*g);
    #pragma unroll
    for (int j = 0; j < 4; ++j) bias[mf][j] = t[j];
  }
  const int tgb = tile*64 + l15;

  // ---- gate: waves 4-7 write sigma(in_act_hi); waves 0-3 tanh*sigma in place ----
  if (w >= 4){
    #pragma unroll
    for (int mf = 0; mf < 4; ++mf){
      #pragma unroll
      for (int nf = 0; nf < 4; ++nf){
        int tl = nf*16 + l15;
        s4v pk;
        #pragma unroll
        for (int j = 0; j < 4; ++j){
          int o = orow + mf*16 + 4*g + j;
          float x = acc[mf][nf][j] + bias[mf][j] + b2f(condl[(size_t)o*T_LEN + tgb + nf*16]);
          x = fminf(fmaxf(x, -30.f), 30.f);
          pk[j] = f2b(1.f/(1.f + __expf(-x)));
        }
        int cb0 = (orow - NCH) + mf*16 + 4*g;
        *(s4v*)(xb + tl*NCH + (cb0 ^ ((tl & 7) << 3))) = pk;
      }
    }
  }
  __syncthreads();
  if (w < 4){
    #pragma unroll
    for (int mf = 0; mf < 4; ++mf){
      #pragma unroll
      for (int nf = 0; nf < 4; ++nf){
        int tl = nf*16 + l15;
        int cb0 = orow + mf*16 + 4*g;
        short* p = xb + tl*NCH + (cb0 ^ ((tl & 7) << 3));
        s4v sg = *(const s4v*)p;
        s4v pk;
        #pragma unroll
        for (int j = 0; j < 4; ++j){
          int o = orow + mf*16 + 4*g + j;
          float x = acc[mf][nf][j] + bias[mf][j] + b2f(condl[(size_t)o*T_LEN + tgb + nf*16]);
          x = fminf(fmaxf(x, -30.f), 30.f);
          float e = __expf(2.f*x);
          float th = (e - 1.f)/(e + 1.f);
          pk[j] = f2b(th * b2f(sg[j]));
        }
        *(s4v*)p = pk;
      }
    }
  }
  __syncthreads();

  // ---- phase 2: res/skip 1x1 GEMM, K=256 ----
  #pragma unroll
  for (int mf = 0; mf < 4; ++mf)
    #pragma unroll
    for (int nf = 0; nf < 4; ++nf) acc[mf][nf] = (f4){0.f,0.f,0.f,0.f};
  #pragma unroll
  for (int kk = 0; kk < 8; ++kk){
    bh8 av[4], bv[4];
    #pragma unroll
    for (int mf = 0; mf < 4; ++mf)
      av[mf] = *(const bh8*)(W2l + (size_t)(orow + mf*16 + l15)*NCH + kk*32 + g*8);
    #pragma unroll
    for (int nf = 0; nf < 4; ++nf){
      int t = nf*16 + l15;
      bv[nf] = *(const bh8*)(xb + t*NCH + ((kk*32 + g*8) ^ ((t & 7) << 3)));
    }
    #pragma unroll
    for (int mf = 0; mf < 4; ++mf)
      #pragma unroll
      for (int nf = 0; nf < 4; ++nf)
        acc[mf][nf] = MFMA(av[mf], bv[nf], acc[mf][nf]);
  }

  float rbv[4][4];
  #pragma unroll
  for (int mf = 0; mf < 4; ++mf){
    f4 t = *(const f4*)(rsb_l + orow + mf*16 + 4*g);
    #pragma unroll
    for (int j = 0; j < 4; ++j) rbv[mf][j] = t[j];
  }

  // ---- epilogue: h += rs[:256] ; out += rs[256:] ----
  if (w < 4){
    #pragma unroll
    for (int mf = 0; mf < 4; ++mf){
      #pragma unroll
      for (int nf = 0; nf < 4; ++nf){
        int tl = nf*16 + l15;
        int cb0 = orow + mf*16 + 4*g;
        s4v hold = *(const s4v*)(Ht + 16384 + tl*NCH + (cb0 ^ ((tl & 7) << 3)));  // center tap
        s4v pk;
        #pragma unroll
        for (int j = 0; j < 4; ++j)
          pk[j] = f2b(b2f(hold[j]) + acc[mf][nf][j] + rbv[mf][j]);
        *(s4v*)(hDst + ((size_t)b*HROWS + PAD + tile*64 + tl)*NCH + cb0) = pk;
      }
    }
  } else {
    #pragma unroll
    for (int mf = 0; mf < 4; ++mf){
      #pragma unroll
      for (int nf = 0; nf < 4; ++nf){
        int tl = nf*16 + l15;
        int co = (orow - NCH) + mf*16 + 4*g;
        short* op = outb + ((size_t)b*T_LEN + tile*64 + tl)*NCH + co;
        s4v prev = *(const s4v*)op;
        s4v pk;
        #pragma unroll
        for (int j = 0; j < 4; ++j)
          pk[j] = f2b(b2f(prev[j]) + acc[mf][nf][j] + rbv[mf][j]);
        *(s4v*)op = pk;
      }
    }
  }
}

// ---------------- final: y = end_w @ out + end_b, split halves ----------------
__global__ void final_k(const short* __restrict__ outb, const float* __restrict__ end_w,
                        const float* __restrict__ end_b, float* __restrict__ y){
  __shared__ float ew[16*NCH];
  __shared__ float eb[16];
  int b = blockIdx.y, t0 = blockIdx.x*64;
  for (int i = threadIdx.x; i < 16*NCH; i += 256) ew[i] = end_w[i];
  if (threadIdx.x < 16) eb[threadIdx.x] = end_b[threadIdx.x];
  __syncthreads();
  int t = t0 + (threadIdx.x & 63), og = threadIdx.x >> 6;
  float acc[4];
  #pragma unroll
  for (int j = 0; j < 4; ++j) acc[j] = eb[og*4 + j];
  const short* row = outb + ((size_t)b*T_LEN + t)*NCH;
  for (int c = 0; c < NCH; c += 8){
    bh8 v = *(const bh8*)(row + c);
    #pragma unroll
    for (int i = 0; i < 8; ++i){
      float f = b2f(v[i]);
      #pragma unroll
      for (int j = 0; j < 4; ++j) acc[j] += f * ew[(og*4 + j)*NCH + c + i];
    }
  }
  #pragma unroll
  for (int j = 0; j < 4; ++j){
    int o = og*4 + j;
    float* dst = (o < 8) ? (y + ((size_t)(b*8 + o))*T_LEN)
                         : (y + 131072 + ((size_t)(b*8 + o - 8))*T_LEN);
    dst[t] = acc[j];
  }
}

extern "C" void kernel_launch(void* const* d_in, const int* in_sizes, int n_in,
                              void* d_out, int out_size, void* d_ws, size_t ws_size,
                              hipStream_t stream){
  const float* audio      = (const float*)d_in[0];
  const float* spect      = (const float*)d_in[1];
  const int*   pos        = (const int*)  d_in[2];
  const float* start_w    = (const float*)d_in[3];
  const float* start_b    = (const float*)d_in[4];
  const float* cond_w     = (const float*)d_in[5];
  const float* cond_b     = (const float*)d_in[6];
  const float* pos_emb_w  = (const float*)d_in[7];
  const float* pos_lin_w  = (const float*)d_in[8];
  const float* pos_lin_b  = (const float*)d_in[9];
  const float* in_w       = (const float*)d_in[10];
  const float* in_b       = (const float*)d_in[11];
  const float* rs_w       = (const float*)d_in[12];
  const float* rs_b       = (const float*)d_in[13];
  const float* rs_last_w  = (const float*)d_in[14];
  const float* rs_last_b  = (const float*)d_in[15];
  const float* end_w      = (const float*)d_in[16];
  const float* end_b      = (const float*)d_in[17];
  float* y = (float*)d_out;

  char* ws = (char*)d_ws;
  size_t off = 0;
  auto alloc = [&](size_t bytes) -> void* {
    void* p = ws + off;
    off += (bytes + 255) & ~(size_t)255;
    return p;
  };
  const size_t hBytes   = (size_t)BG*HROWS*NCH*2;     // 8,912,896
  const size_t condBy   = (size_t)4096*T_LEN*2;       // 33,554,432
  const size_t outBy    = (size_t)BG*T_LEN*NCH*2;     // 8,388,608
  short* hA   = (short*)alloc(hBytes);
  short* hB   = (short*)alloc(hBytes);
  short* cond = (short*)alloc(condBy);
  short* outb = (short*)alloc(outBy);
  short* W1   = (short*)alloc((size_t)NL*3*M2*NCH*2);
  short* W2   = (short*)alloc((size_t)NL*M2*NCH*2);
  float* rsb8 = (float*)alloc((size_t)NL*M2*4);
  float* cb   = (float*)alloc((size_t)BG*4096*4);
  if (off > ws_size) return;  // insufficient workspace -> output stays zero (diagnosable)

  hipMemsetAsync(hA, 0, hBytes, stream);
  hipMemsetAsync(hB, 0, hBytes, stream);
  hipMemsetAsync(outb, 0, outBy, stream);

  prep_w <<<4096, 256, 0, stream>>>(in_w, rs_w, rs_last_w, rs_b, rs_last_b, W1, W2, rsb8);
  prep_cb<<<dim3(16, BG), 256, 0, stream>>>(pos, pos_emb_w, pos_lin_w, pos_lin_b, in_b, cb);
  prep_h0<<<dim3(64, BG), 256, 0, stream>>>(audio, start_w, start_b, hA);
  cond_k <<<dim3(64, 128), 256, 0, stream>>>(spect, cond_w, cond_b, cond);

  for (int l = 0; l < NL; ++l){
    const short* hS = (l & 1) ? hB : hA;
    short*       hD = (l & 1) ? hA : hB;
    wn_layer<<<dim3(64, BG), 512, 0, stream>>>(
        hS, hD,
        W1 + (size_t)l*3*M2*NCH,
        W2 + (size_t)l*M2*NCH,
        cond + (size_t)l*M2*T_LEN,
        cb + l*M2,
        rsb8 + l*M2,
        outb, 1 << l);
  }
  final_k<<<dim3(64, BG), 256, 0, stream>>>(outb, end_w, end_b, y);
}

// Round 2
// 459.387 us; speedup vs baseline: 2.1541x; 2.1541x over previous
//
#include <hip/hip_runtime.h>
#include <stdint.h>

#define T_LEN 4096
#define PAD   128
#define HROWS (T_LEN + 2*PAD)   // 4352 rows (zero pad 128 each side)
#define NCH   256
#define M2    512
#define BG    4
#define NL    8

using f4  = __attribute__((ext_vector_type(4))) float;
using bh8 = __attribute__((ext_vector_type(8))) short;
using s4v = __attribute__((ext_vector_type(4))) short;
using u4  = __attribute__((ext_vector_type(4))) unsigned int;

static __device__ __forceinline__ short f2b(float f){
  unsigned u = __builtin_bit_cast(unsigned, f);
  unsigned r = (u + 0x7FFFu + ((u >> 16) & 1u)) >> 16;
  return (short)r;
}
static __device__ __forceinline__ float b2f(short s){
  unsigned u = ((unsigned)(unsigned short)s) << 16;
  return __builtin_bit_cast(float, u);
}

#define MFMA(a,b,c) __builtin_amdgcn_mfma_f32_16x16x32_bf16((a),(b),(c),0,0,0)

// ---------------- prep: weights -> bf16, relayout ----------------
// W1[l][tap][o][c] = in_w[l][o][c][tap]
// W2[l][o][c]: l<7 -> rs_w[l][o][c]; l==7: o<256 -> 0 else rs_last_w[o-256][c]
// rsb8[l][o]:  l<7 -> rs_b[l][o];    l==7: o<256 -> 0 else rs_last_b[o-256]
// Wc[o][k] (k padded 80->128) = cond_w[o][k]
__global__ void prep_w(const float* __restrict__ in_w, const float* __restrict__ rs_w,
                       const float* __restrict__ rs_last_w, const float* __restrict__ rs_b,
                       const float* __restrict__ rs_last_b, const float* __restrict__ cond_w,
                       short* __restrict__ W1, short* __restrict__ W2, float* __restrict__ rsb8,
                       short* __restrict__ Wc){
  const int n1 = NL*3*M2*NCH;           // 3,145,728
  const int n2 = NL*M2*NCH;             // 1,048,576
  const int n3 = NL*M2;                 // 4,096
  const int n4 = 4096*128;              // 524,288
  for (int i = blockIdx.x*blockDim.x + threadIdx.x; i < n1+n2+n3+n4; i += gridDim.x*blockDim.x){
    if (i < n1){
      int c = i & 255, o = (i >> 8) & 511, lt = i >> 17;
      int tap = lt % 3, l = lt / 3;
      W1[i] = f2b(in_w[(((l*M2 + o)*NCH + c)*3) + tap]);
    } else if (i < n1+n2){
      int j = i - n1;
      int c = j & 255, o = (j >> 8) & 511, l = j >> 17;
      float v;
      if (l < 7) v = rs_w[(l*M2 + o)*NCH + c];
      else       v = (o < NCH) ? 0.f : rs_last_w[(o-NCH)*NCH + c];
      W2[j] = f2b(v);
    } else if (i < n1+n2+n3){
      int k = i - n1 - n2;
      int o = k & 511, l = k >> 9;
      float v;
      if (l < 7) v = rs_b[l*M2 + o];
      else       v = (o < NCH) ? 0.f : rs_last_b[o-NCH];
      rsb8[k] = v;
    } else {
      int j = i - n1 - n2 - n3;
      int k = j & 127, o = j >> 7;
      Wc[j] = (k < 80) ? f2b(cond_w[o*80 + k]) : (short)0;
    }
  }
}

// ---------------- prep: spectT[t][128 k] bf16 (padded transpose) ----------------
__global__ void prep_spectT(const float* __restrict__ spect, short* __restrict__ spectT){
  __shared__ float tile[64][65];
  int t0 = blockIdx.x*64, k0 = blockIdx.y*64;
  for (int i = threadIdx.x; i < 64*64; i += 256){
    int kr = i >> 6, tt = i & 63;
    int k = k0 + kr;
    tile[kr][tt] = (k < 80) ? spect[(size_t)k*T_LEN + t0 + tt] : 0.f;
  }
  __syncthreads();
  for (int i = threadIdx.x; i < 64*64; i += 256){
    int r = i >> 6, kk = i & 63;
    spectT[(size_t)(t0 + r)*128 + k0 + kk] = f2b(tile[kk][r]);
  }
}

// ---------------- prep: cb[b][ch] = in_b[ch] + pos_lin_b[ch] + pc[b][ch] ----------------
__global__ void prep_cb(const int* __restrict__ pos, const float* __restrict__ pos_emb_w,
                        const float* __restrict__ pos_lin_w, const float* __restrict__ pos_lin_b,
                        const float* __restrict__ in_b, float* __restrict__ cb){
  int b = blockIdx.y;
  int ch = blockIdx.x*blockDim.x + threadIdx.x;     // 0..4095
  int p = pos[b];
  float acc = pos_lin_b[ch] + in_b[ch];
  for (int k = 0; k < 128; ++k){
    float e = pos_emb_w[p*128 + k];
    e = e > 0.f ? e : 0.f;
    acc += e * pos_lin_w[ch*128 + k];
  }
  cb[b*4096 + ch] = acc;
}

// ---------------- prep: h0[b][t][c] (bf16, padded layout) ----------------
__global__ void prep_h0(const float* __restrict__ audio, const float* __restrict__ start_w,
                        const float* __restrict__ start_b, short* __restrict__ hA){
  __shared__ float sw[NCH*8];
  __shared__ float sb[NCH];
  int b = blockIdx.y, t0 = blockIdx.x*64;
  for (int i = threadIdx.x; i < NCH*8; i += 256) sw[i] = start_w[i];
  for (int i = threadIdx.x; i < NCH;   i += 256) sb[i] = start_b[i];
  __syncthreads();
  int t = t0 + (threadIdx.x & 63);
  int cg = threadIdx.x >> 6;
  float av[8];
  #pragma unroll
  for (int ic = 0; ic < 8; ++ic) av[ic] = audio[((size_t)(b*8 + ic))*T_LEN + t];
  short* dst = hA + ((size_t)b*HROWS + PAD + t)*NCH;
  for (int c = cg*64; c < cg*64 + 64; ++c){
    float acc = sb[c];
    #pragma unroll
    for (int ic = 0; ic < 8; ++ic) acc += sw[c*8 + ic]*av[ic];
    dst[c] = f2b(acc);
  }
}

// ---------------- cond GEMM: cond[l][t][512] = Wc @ spect + cond_b (bf16 MFMA) ----------------
// grid (64 t-tiles, 8 ch-tiles of 512), 512 threads (8 waves), K=96 (padded from 80)
__global__ __launch_bounds__(512, 2) void cond_gemm(
    const short* __restrict__ Wc, const short* __restrict__ spectT,
    const float* __restrict__ cond_b, short* __restrict__ cond){
  __shared__ short St[64*128];   // 16 KB, [t][k] XOR-swizzled
  const int tid = threadIdx.x;
  const int w = tid >> 6, lane = tid & 63;
  const int l15 = lane & 15, g = lane >> 4;
  const int t0 = blockIdx.x*64, ch0 = blockIdx.y*512;
  const int orow = w << 6;

  #pragma unroll
  for (int s = 0; s < 2; ++s){
    int id = tid + s*512;
    int r = id >> 4, c8 = (id & 15) << 3;
    u4 v = *(const u4*)(spectT + (size_t)(t0 + r)*128 + c8);
    *(u4*)(St + r*128 + (c8 ^ ((r & 7) << 3))) = v;
  }
  __syncthreads();

  f4 acc[4][4];
  #pragma unroll
  for (int mf = 0; mf < 4; ++mf)
    #pragma unroll
    for (int nf = 0; nf < 4; ++nf) acc[mf][nf] = (f4){0.f,0.f,0.f,0.f};

  #pragma unroll
  for (int kk = 0; kk < 3; ++kk){
    bh8 av[4], bv[4];
    #pragma unroll
    for (int mf = 0; mf < 4; ++mf)
      av[mf] = *(const bh8*)(Wc + (size_t)(ch0 + orow + mf*16 + l15)*128 + kk*32 + g*8);
    #pragma unroll
    for (int nf = 0; nf < 4; ++nf){
      int t = nf*16 + l15;
      bv[nf] = *(const bh8*)(St + t*128 + ((kk*32 + g*8) ^ ((t & 7) << 3)));
    }
    #pragma unroll
    for (int mf = 0; mf < 4; ++mf)
      #pragma unroll
      for (int nf = 0; nf < 4; ++nf)
        acc[mf][nf] = MFMA(av[mf], bv[nf], acc[mf][nf]);
  }

  #pragma unroll
  for (int mf = 0; mf < 4; ++mf){
    f4 bb = *(const f4*)(cond_b + ch0 + orow + mf*16 + 4*g);
    #pragma unroll
    for (int nf = 0; nf < 4; ++nf){
      int t = t0 + nf*16 + l15;
      int c = orow + mf*16 + 4*g;
      s4v pk;
      #pragma unroll
      for (int j = 0; j < 4; ++j) pk[j] = f2b(acc[mf][nf][j] + bb[j]);
      *(s4v*)(cond + ((size_t)blockIdx.y*T_LEN + t)*512 + c) = pk;
    }
  }
}

// ---------------- fused WaveNet layer ----------------
// grid (64 t-tiles, 4 batch), 512 threads (8 waves). 1 block/CU (128 KB LDS).
__global__ __launch_bounds__(512, 2) void wn_layer(
    const short* __restrict__ hSrc, short* __restrict__ hDst,
    const short* __restrict__ W1l, const short* __restrict__ W2l,
    const short* __restrict__ condl, const float* __restrict__ cb_l,
    const float* __restrict__ rsb_l, short* __restrict__ outb, int dil){

  __shared__ short Ht[3*64*NCH];   // 96 KB: 3 tap windows [64 t][256 c], XOR-swizzled
  __shared__ short xb[64*NCH];     // 32 KB: sigma exchange, then acts[t][c]

  const int tid  = threadIdx.x;
  const int w    = tid >> 6, lane = tid & 63;
  const int l15  = lane & 15, g = lane >> 4;
  const int tile = blockIdx.x, b = blockIdx.y;
  const int orow = w << 6;

  // ---- stage 3 h windows: global linear read -> swizzled LDS write ----
  {
    const int rsub = tid >> 5;            // 0..15
    const int innr = (tid & 31) << 3;     // short offset in row, 16B chunks
    #pragma unroll
    for (int tap = 0; tap < 3; ++tap){
      const int gbase = b*HROWS + PAD + tile*64 + (tap-1)*dil;
      #pragma unroll
      for (int ch = 0; ch < 4; ++ch){
        int r = ch*16 + rsub;
        u4 v = *(const u4*)(hSrc + (size_t)(gbase + r)*NCH + innr);
        *(u4*)(Ht + tap*16384 + r*NCH + (innr ^ ((r & 7) << 3))) = v;
      }
    }
  }
  __syncthreads();

  f4 acc[4][4];
  #pragma unroll
  for (int mf = 0; mf < 4; ++mf)
    #pragma unroll
    for (int nf = 0; nf < 4; ++nf) acc[mf][nf] = (f4){0.f,0.f,0.f,0.f};

  // ---- phase 1: dilated conv as 3 GEMMs, K=256 each ----
  #pragma unroll
  for (int tap = 0; tap < 3; ++tap){
    const short* Wt = W1l + ((size_t)(tap*M2 + orow))*NCH;
    #pragma unroll
    for (int kk = 0; kk < 8; ++kk){
      bh8 av[4], bv[4];
      #pragma unroll
      for (int mf = 0; mf < 4; ++mf)
        av[mf] = *(const bh8*)(Wt + (size_t)(mf*16 + l15)*NCH + kk*32 + g*8);
      #pragma unroll
      for (int nf = 0; nf < 4; ++nf){
        int t = nf*16 + l15;
        bv[nf] = *(const bh8*)(Ht + tap*16384 + t*NCH + ((kk*32 + g*8) ^ ((t & 7) << 3)));
      }
      #pragma unroll
      for (int mf = 0; mf < 4; ++mf)
        #pragma unroll
        for (int nf = 0; nf < 4; ++nf)
          acc[mf][nf] = MFMA(av[mf], bv[nf], acc[mf][nf]);
    }
  }

  // per-(mf,j) bias = cb (in_b + pos_lin_b + pc)
  float bias[4][4];
  #pragma unroll
  for (int mf = 0; mf < 4; ++mf){
    f4 t = *(const f4*)(cb_l + b*4096 + orow + mf*16 + 4*g);
    #pragma unroll
    for (int j = 0; j < 4; ++j) bias[mf][j] = t[j];
  }

  // ---- gate: waves 4-7 write sigma(in_act_hi); waves 0-3 tanh*sigma in place ----
  if (w >= 4){
    #pragma unroll
    for (int mf = 0; mf < 4; ++mf){
      #pragma unroll
      for (int nf = 0; nf < 4; ++nf){
        int tl = nf*16 + l15;
        s4v cv = *(const s4v*)(condl + (size_t)(tile*64 + tl)*512 + orow + mf*16 + 4*g);
        s4v pk;
        #pragma unroll
        for (int j = 0; j < 4; ++j){
          float x = acc[mf][nf][j] + bias[mf][j] + b2f(cv[j]);
          x = fminf(fmaxf(x, -30.f), 30.f);
          pk[j] = f2b(1.f/(1.f + __expf(-x)));
        }
        int cb0 = (orow - NCH) + mf*16 + 4*g;
        *(s4v*)(xb + tl*NCH + (cb0 ^ ((tl & 7) << 3))) = pk;
      }
    }
  }
  __syncthreads();
  if (w < 4){
    #pragma unroll
    for (int mf = 0; mf < 4; ++mf){
      #pragma unroll
      for (int nf = 0; nf < 4; ++nf){
        int tl = nf*16 + l15;
        s4v cv = *(const s4v*)(condl + (size_t)(tile*64 + tl)*512 + orow + mf*16 + 4*g);
        int cb0 = orow + mf*16 + 4*g;
        short* p = xb + tl*NCH + (cb0 ^ ((tl & 7) << 3));
        s4v sg = *(const s4v*)p;
        s4v pk;
        #pragma unroll
        for (int j = 0; j < 4; ++j){
          float x = acc[mf][nf][j] + bias[mf][j] + b2f(cv[j]);
          x = fminf(fmaxf(x, -30.f), 30.f);
          float e = __expf(2.f*x);
          float th = (e - 1.f)/(e + 1.f);
          pk[j] = f2b(th * b2f(sg[j]));
        }
        *(s4v*)p = pk;
      }
    }
  }
  __syncthreads();

  // ---- phase 2: res/skip 1x1 GEMM, K=256 ----
  #pragma unroll
  for (int mf = 0; mf < 4; ++mf)
    #pragma unroll
    for (int nf = 0; nf < 4; ++nf) acc[mf][nf] = (f4){0.f,0.f,0.f,0.f};
  #pragma unroll
  for (int kk = 0; kk < 8; ++kk){
    bh8 av[4], bv[4];
    #pragma unroll
    for (int mf = 0; mf < 4; ++mf)
      av[mf] = *(const bh8*)(W2l + (size_t)(orow + mf*16 + l15)*NCH + kk*32 + g*8);
    #pragma unroll
    for (int nf = 0; nf < 4; ++nf){
      int t = nf*16 + l15;
      bv[nf] = *(const bh8*)(xb + t*NCH + ((kk*32 + g*8) ^ ((t & 7) << 3)));
    }
    #pragma unroll
    for (int mf = 0; mf < 4; ++mf)
      #pragma unroll
      for (int nf = 0; nf < 4; ++nf)
        acc[mf][nf] = MFMA(av[mf], bv[nf], acc[mf][nf]);
  }

  float rbv[4][4];
  #pragma unroll
  for (int mf = 0; mf < 4; ++mf){
    f4 t = *(const f4*)(rsb_l + orow + mf*16 + 4*g);
    #pragma unroll
    for (int j = 0; j < 4; ++j) rbv[mf][j] = t[j];
  }

  // ---- epilogue: h += rs[:256] ; out += rs[256:] ----
  if (w < 4){
    #pragma unroll
    for (int mf = 0; mf < 4; ++mf){
      #pragma unroll
      for (int nf = 0; nf < 4; ++nf){
        int tl = nf*16 + l15;
        int cb0 = orow + mf*16 + 4*g;
        s4v hold = *(const s4v*)(Ht + 16384 + tl*NCH + (cb0 ^ ((tl & 7) << 3)));  // center tap
        s4v pk;
        #pragma unroll
        for (int j = 0; j < 4; ++j)
          pk[j] = f2b(b2f(hold[j]) + acc[mf][nf][j] + rbv[mf][j]);
        *(s4v*)(hDst + ((size_t)b*HROWS + PAD + tile*64 + tl)*NCH + cb0) = pk;
      }
    }
  } else {
    #pragma unroll
    for (int mf = 0; mf < 4; ++mf){
      #pragma unroll
      for (int nf = 0; nf < 4; ++nf){
        int tl = nf*16 + l15;
        int co = (orow - NCH) + mf*16 + 4*g;
        short* op = outb + ((size_t)b*T_LEN + tile*64 + tl)*NCH + co;
        s4v prev = *(const s4v*)op;
        s4v pk;
        #pragma unroll
        for (int j = 0; j < 4; ++j)
          pk[j] = f2b(b2f(prev[j]) + acc[mf][nf][j] + rbv[mf][j]);
        *(s4v*)op = pk;
      }
    }
  }
}

// ---------------- final: y = end_w @ out + end_b, split halves ----------------
__global__ void final_k(const short* __restrict__ outb, const float* __restrict__ end_w,
                        const float* __restrict__ end_b, float* __restrict__ y){
  __shared__ float ew[16*NCH];
  __shared__ float eb[16];
  int b = blockIdx.y, t0 = blockIdx.x*64;
  for (int i = threadIdx.x; i < 16*NCH; i += 256) ew[i] = end_w[i];
  if (threadIdx.x < 16) eb[threadIdx.x] = end_b[threadIdx.x];
  __syncthreads();
  int t = t0 + (threadIdx.x & 63), og = threadIdx.x >> 6;
  float acc[4];
  #pragma unroll
  for (int j = 0; j < 4; ++j) acc[j] = eb[og*4 + j];
  const short* row = outb + ((size_t)b*T_LEN + t)*NCH;
  for (int c = 0; c < NCH; c += 8){
    bh8 v = *(const bh8*)(row + c);
    #pragma unroll
    for (int i = 0; i < 8; ++i){
      float f = b2f(v[i]);
      #pragma unroll
      for (int j = 0; j < 4; ++j) acc[j] += f * ew[(og*4 + j)*NCH + c + i];
    }
  }
  #pragma unroll
  for (int j = 0; j < 4; ++j){
    int o = og*4 + j;
    float* dst = (o < 8) ? (y + ((size_t)(b*8 + o))*T_LEN)
                         : (y + 131072 + ((size_t)(b*8 + o - 8))*T_LEN);
    dst[t] = acc[j];
  }
}

extern "C" void kernel_launch(void* const* d_in, const int* in_sizes, int n_in,
                              void* d_out, int out_size, void* d_ws, size_t ws_size,
                              hipStream_t stream){
  const float* audio      = (const float*)d_in[0];
  const float* spect      = (const float*)d_in[1];
  const int*   pos        = (const int*)  d_in[2];
  const float* start_w    = (const float*)d_in[3];
  const float* start_b    = (const float*)d_in[4];
  const float* cond_w     = (const float*)d_in[5];
  const float* cond_b     = (const float*)d_in[6];
  const float* pos_emb_w  = (const float*)d_in[7];
  const float* pos_lin_w  = (const float*)d_in[8];
  const float* pos_lin_b  = (const float*)d_in[9];
  const float* in_w       = (const float*)d_in[10];
  const float* in_b       = (const float*)d_in[11];
  const float* rs_w       = (const float*)d_in[12];
  const float* rs_b       = (const float*)d_in[13];
  const float* rs_last_w  = (const float*)d_in[14];
  const float* rs_last_b  = (const float*)d_in[15];
  const float* end_w      = (const float*)d_in[16];
  const float* end_b      = (const float*)d_in[17];
  float* y = (float*)d_out;

  char* ws = (char*)d_ws;
  size_t off = 0;
  auto alloc = [&](size_t bytes) -> void* {
    void* p = ws + off;
    off += (bytes + 255) & ~(size_t)255;
    return p;
  };
  const size_t hBytes   = (size_t)BG*HROWS*NCH*2;     // 8,912,896
  const size_t condBy   = (size_t)4096*T_LEN*2;       // 33,554,432 ([l][t][512])
  const size_t outBy    = (size_t)BG*T_LEN*NCH*2;     // 8,388,608
  short* hA     = (short*)alloc(hBytes);
  short* hB     = (short*)alloc(hBytes);
  short* cond   = (short*)alloc(condBy);
  short* outb   = (short*)alloc(outBy);
  short* W1     = (short*)alloc((size_t)NL*3*M2*NCH*2);
  short* W2     = (short*)alloc((size_t)NL*M2*NCH*2);
  float* rsb8   = (float*)alloc((size_t)NL*M2*4);
  float* cb     = (float*)alloc((size_t)BG*4096*4);
  short* Wc     = (short*)alloc((size_t)4096*128*2);
  short* spectT = (short*)alloc((size_t)4096*128*2);
  if (off > ws_size) return;  // insufficient workspace -> output stays zero (diagnosable)

  hipMemsetAsync(hA, 0, hBytes, stream);
  hipMemsetAsync(hB, 0, hBytes, stream);
  hipMemsetAsync(outb, 0, outBy, stream);

  prep_w <<<4096, 256, 0, stream>>>(in_w, rs_w, rs_last_w, rs_b, rs_last_b, cond_w,
                                    W1, W2, rsb8, Wc);
  prep_spectT<<<dim3(64, 2), 256, 0, stream>>>(spect, spectT);
  prep_cb<<<dim3(16, BG), 256, 0, stream>>>(pos, pos_emb_w, pos_lin_w, pos_lin_b, in_b, cb);
  prep_h0<<<dim3(64, BG), 256, 0, stream>>>(audio, start_w, start_b, hA);
  cond_gemm<<<dim3(64, 8), 512, 0, stream>>>(Wc, spectT, cond_b, cond);

  for (int l = 0; l < NL; ++l){
    const short* hS = (l & 1) ? hB : hA;
    short*       hD = (l & 1) ? hA : hB;
    wn_layer<<<dim3(64, BG), 512, 0, stream>>>(
        hS, hD,
        W1 + (size_t)l*3*M2*NCH,
        W2 + (size_t)l*M2*NCH,
        cond + (size_t)l*T_LEN*512,
        cb + l*M2,
        rsb8 + l*M2,
        outb, 1 << l);
  }
  final_k<<<dim3(64, BG), 256, 0, stream>>>(outb, end_w, end_b, y);
}

// Round 3
// 343.845 us; speedup vs baseline: 2.8780x; 1.3360x over previous
//
#include <hip/hip_runtime.h>
#include <stdint.h>

#define T_LEN 4096
#define PAD   128
#define HROWS (T_LEN + 2*PAD)   // 4352 rows (zero pad 128 each side)
#define NCH   256
#define M2    512
#define BG    4
#define NL    8

using f4  = __attribute__((ext_vector_type(4))) float;
using bh8 = __attribute__((ext_vector_type(8))) short;
using s4v = __attribute__((ext_vector_type(4))) short;
using u4  = __attribute__((ext_vector_type(4))) unsigned int;

static __device__ __forceinline__ short f2b(float f){
  unsigned u = __builtin_bit_cast(unsigned, f);
  unsigned r = (u + 0x7FFFu + ((u >> 16) & 1u)) >> 16;
  return (short)r;
}
static __device__ __forceinline__ float b2f(short s){
  unsigned u = ((unsigned)(unsigned short)s) << 16;
  return __builtin_bit_cast(float, u);
}

#define MFMA(a,b,c) __builtin_amdgcn_mfma_f32_16x16x32_bf16((a),(b),(c),0,0,0)

// ---------------- prep: weights -> bf16, fragment-ordered relayout ----------------
// W1s[l][tap][og][kk][mf][lane][8]: o = og*64+mf*16+(lane&15), c = kk*32+(lane>>4)*8+j
// W2s[l][og][kk][mf][lane][8]: same o/c mapping; l<7 rs_w, l==7: o<256 -> 0 else rs_last_w
// rsb8[l][o]:  l<7 -> rs_b[l][o]; l==7: o<256 -> 0 else rs_last_b[o-256]
// Wc[o][k] (k padded 80->128) = cond_w[o][k]
__global__ void prep_w(const float* __restrict__ in_w, const float* __restrict__ rs_w,
                       const float* __restrict__ rs_last_w, const float* __restrict__ rs_b,
                       const float* __restrict__ rs_last_b, const float* __restrict__ cond_w,
                       short* __restrict__ W1, short* __restrict__ W2, float* __restrict__ rsb8,
                       short* __restrict__ Wc){
  const int n1 = NL*3*M2*NCH;           // 3,145,728
  const int n2 = NL*M2*NCH;             // 1,048,576
  const int n3 = NL*M2;                 // 4,096
  const int n4 = 4096*128;              // 524,288
  for (int i = blockIdx.x*blockDim.x + threadIdx.x; i < n1+n2+n3+n4; i += gridDim.x*blockDim.x){
    if (i < n1){
      int j = i & 7, lane = (i >> 3) & 63, mf = (i >> 9) & 3, kk = (i >> 11) & 7, og = (i >> 14) & 7;
      int lt = i >> 17;                 // l*3 + tap
      int tap = lt % 3, l = lt / 3;
      int o = og*64 + mf*16 + (lane & 15);
      int c = kk*32 + (lane >> 4)*8 + j;
      W1[i] = f2b(in_w[(((l*M2 + o)*NCH + c)*3) + tap]);
    } else if (i < n1+n2){
      int q = i - n1;
      int j = q & 7, lane = (q >> 3) & 63, mf = (q >> 9) & 3, kk = (q >> 11) & 7, og = (q >> 14) & 7;
      int l = q >> 17;
      int o = og*64 + mf*16 + (lane & 15);
      int c = kk*32 + (lane >> 4)*8 + j;
      float v;
      if (l < 7) v = rs_w[(l*M2 + o)*NCH + c];
      else       v = (o < NCH) ? 0.f : rs_last_w[(o-NCH)*NCH + c];
      W2[q] = f2b(v);
    } else if (i < n1+n2+n3){
      int k = i - n1 - n2;
      int o = k & 511, l = k >> 9;
      float v;
      if (l < 7) v = rs_b[l*M2 + o];
      else       v = (o < NCH) ? 0.f : rs_last_b[o-NCH];
      rsb8[k] = v;
    } else {
      int j = i - n1 - n2 - n3;
      int k = j & 127, o = j >> 7;
      Wc[j] = (k < 80) ? f2b(cond_w[o*80 + k]) : (short)0;
    }
  }
}

// ---------------- prep: spectT[t][128 k] bf16 (padded transpose) ----------------
__global__ void prep_spectT(const float* __restrict__ spect, short* __restrict__ spectT){
  __shared__ float tile[64][65];
  int t0 = blockIdx.x*64, k0 = blockIdx.y*64;
  for (int i = threadIdx.x; i < 64*64; i += 256){
    int kr = i >> 6, tt = i & 63;
    int k = k0 + kr;
    tile[kr][tt] = (k < 80) ? spect[(size_t)k*T_LEN + t0 + tt] : 0.f;
  }
  __syncthreads();
  for (int i = threadIdx.x; i < 64*64; i += 256){
    int r = i >> 6, kk = i & 63;
    spectT[(size_t)(t0 + r)*128 + k0 + kk] = f2b(tile[kk][r]);
  }
}

// ---------------- prep: cb[b][ch] = in_b[ch] + pos_lin_b[ch] + pc[b][ch] ----------------
__global__ void prep_cb(const int* __restrict__ pos, const float* __restrict__ pos_emb_w,
                        const float* __restrict__ pos_lin_w, const float* __restrict__ pos_lin_b,
                        const float* __restrict__ in_b, float* __restrict__ cb){
  int b = blockIdx.y;
  int ch = blockIdx.x*blockDim.x + threadIdx.x;     // 0..4095
  int p = pos[b];
  float acc = pos_lin_b[ch] + in_b[ch];
  for (int k = 0; k < 128; ++k){
    float e = pos_emb_w[p*128 + k];
    e = e > 0.f ? e : 0.f;
    acc += e * pos_lin_w[ch*128 + k];
  }
  cb[b*4096 + ch] = acc;
}

// ---------------- prep: h0[b][t][c] (bf16, padded layout) ----------------
__global__ void prep_h0(const float* __restrict__ audio, const float* __restrict__ start_w,
                        const float* __restrict__ start_b, short* __restrict__ hA){
  __shared__ float sw[NCH*8];
  __shared__ float sb[NCH];
  int b = blockIdx.y, t0 = blockIdx.x*64;
  for (int i = threadIdx.x; i < NCH*8; i += 256) sw[i] = start_w[i];
  for (int i = threadIdx.x; i < NCH;   i += 256) sb[i] = start_b[i];
  __syncthreads();
  int t = t0 + (threadIdx.x & 63);
  int cg = threadIdx.x >> 6;
  float av[8];
  #pragma unroll
  for (int ic = 0; ic < 8; ++ic) av[ic] = audio[((size_t)(b*8 + ic))*T_LEN + t];
  short* dst = hA + ((size_t)b*HROWS + PAD + t)*NCH;
  for (int c = cg*64; c < cg*64 + 64; ++c){
    float acc = sb[c];
    #pragma unroll
    for (int ic = 0; ic < 8; ++ic) acc += sw[c*8 + ic]*av[ic];
    dst[c] = f2b(acc);
  }
}

// ---------------- cond GEMM: fragment-ordered output ----------------
// condF[l][tile(64)][w(8)][mfnf(16)][lane(64)][4]; grid (64 t-tiles, 8 layers)
__global__ __launch_bounds__(512, 2) void cond_gemm(
    const short* __restrict__ Wc, const short* __restrict__ spectT,
    const float* __restrict__ cond_b, short* __restrict__ cond){
  __shared__ short St[64*128];   // 16 KB, [t][k] XOR-swizzled
  const int tid = threadIdx.x;
  const int w = tid >> 6, lane = tid & 63;
  const int l15 = lane & 15, g = lane >> 4;
  const int t0 = blockIdx.x*64, ch0 = blockIdx.y*512;
  const int orow = w << 6;

  #pragma unroll
  for (int s = 0; s < 2; ++s){
    int id = tid + s*512;
    int r = id >> 4, c8 = (id & 15) << 3;
    u4 v = *(const u4*)(spectT + (size_t)(t0 + r)*128 + c8);
    *(u4*)(St + r*128 + (c8 ^ ((r & 7) << 3))) = v;
  }
  __syncthreads();

  f4 acc[4][4];
  #pragma unroll
  for (int mf = 0; mf < 4; ++mf)
    #pragma unroll
    for (int nf = 0; nf < 4; ++nf) acc[mf][nf] = (f4){0.f,0.f,0.f,0.f};

  #pragma unroll
  for (int kk = 0; kk < 3; ++kk){
    bh8 av[4], bv[4];
    #pragma unroll
    for (int mf = 0; mf < 4; ++mf)
      av[mf] = *(const bh8*)(Wc + (size_t)(ch0 + orow + mf*16 + l15)*128 + kk*32 + g*8);
    #pragma unroll
    for (int nf = 0; nf < 4; ++nf){
      int t = nf*16 + l15;
      bv[nf] = *(const bh8*)(St + t*128 + ((kk*32 + g*8) ^ ((t & 7) << 3)));
    }
    #pragma unroll
    for (int mf = 0; mf < 4; ++mf)
      #pragma unroll
      for (int nf = 0; nf < 4; ++nf)
        acc[mf][nf] = MFMA(av[mf], bv[nf], acc[mf][nf]);
  }

  short* cbase = cond + (((size_t)(blockIdx.y*64 + blockIdx.x)*8 + w)*16)*256 + lane*4;
  #pragma unroll
  for (int mf = 0; mf < 4; ++mf){
    f4 bb = *(const f4*)(cond_b + ch0 + orow + mf*16 + 4*g);
    #pragma unroll
    for (int nf = 0; nf < 4; ++nf){
      s4v pk;
      #pragma unroll
      for (int j = 0; j < 4; ++j) pk[j] = f2b(acc[mf][nf][j] + bb[j]);
      *(s4v*)(cbase + (mf*4 + nf)*256) = pk;
    }
  }
}

// ---------------- fused WaveNet layer ----------------
// grid (64 t-tiles, 4 batch), 512 threads (8 waves). 1 block/CU (128 KB LDS).
__global__ __launch_bounds__(512, 2) void wn_layer(
    const short* __restrict__ hSrc, short* __restrict__ hDst,
    const short* __restrict__ W1l, const short* __restrict__ W2l,
    const short* __restrict__ condl, const float* __restrict__ cb_l,
    const float* __restrict__ rsb_l, short* __restrict__ outF, int dil){

  __shared__ short Ht[3*64*NCH];   // 96 KB: 3 tap windows [64 t][256 c], XOR-swizzled
  __shared__ short xb[64*NCH];     // 32 KB: sigma exchange, then acts[t][c]

  const int tid  = threadIdx.x;
  const int w    = tid >> 6, lane = tid & 63;
  const int l15  = lane & 15, g = lane >> 4;
  const int tile = blockIdx.x, b = blockIdx.y;
  const int orow = w << 6;
  const int sw8  = (l15 & 7) << 3;   // B-read swizzle (t&7 == l15&7 since nf*16 % 8 == 0)

  f4 acc[4][4];
  #pragma unroll
  for (int mf = 0; mf < 4; ++mf)
    #pragma unroll
    for (int nf = 0; nf < 4; ++nf) acc[mf][nf] = (f4){0.f,0.f,0.f,0.f};

  bh8 Ap[2][4], Bp[2][4];

  // coalesced fragment-ordered A loads: 4 KB contiguous per (tap,kk) step
#define LA1(S, BUF) do{ const int _tap=(S)>>3, _kk=(S)&7; \
    const short* _p = W1l + (_tap<<17) + (w<<14) + (_kk<<11) + lane*8; \
    Ap[BUF][0]=*(const bh8*)(_p);      Ap[BUF][1]=*(const bh8*)(_p+512); \
    Ap[BUF][2]=*(const bh8*)(_p+1024); Ap[BUF][3]=*(const bh8*)(_p+1536); }while(0)
#define LB1(S, BUF) do{ const int _tap=(S)>>3, _kk=(S)&7; const int _c=(_kk*32+g*8)^sw8; \
    Bp[BUF][0]=*(const bh8*)(Ht + _tap*16384 + ( 0+l15)*NCH + _c); \
    Bp[BUF][1]=*(const bh8*)(Ht + _tap*16384 + (16+l15)*NCH + _c); \
    Bp[BUF][2]=*(const bh8*)(Ht + _tap*16384 + (32+l15)*NCH + _c); \
    Bp[BUF][3]=*(const bh8*)(Ht + _tap*16384 + (48+l15)*NCH + _c); }while(0)
#define LA2(S, BUF) do{ const int _kk=(S); \
    const short* _p = W2l + (w<<14) + (_kk<<11) + lane*8; \
    Ap[BUF][0]=*(const bh8*)(_p);      Ap[BUF][1]=*(const bh8*)(_p+512); \
    Ap[BUF][2]=*(const bh8*)(_p+1024); Ap[BUF][3]=*(const bh8*)(_p+1536); }while(0)
#define LB2(S, BUF) do{ const int _c=((S)*32+g*8)^sw8; \
    Bp[BUF][0]=*(const bh8*)(xb + ( 0+l15)*NCH + _c); \
    Bp[BUF][1]=*(const bh8*)(xb + (16+l15)*NCH + _c); \
    Bp[BUF][2]=*(const bh8*)(xb + (32+l15)*NCH + _c); \
    Bp[BUF][3]=*(const bh8*)(xb + (48+l15)*NCH + _c); }while(0)

  LA1(0, 0);   // issue first weight fragments before staging

  // ---- stage 3 h windows: global linear read -> swizzled LDS write ----
  {
    const int rsub = tid >> 5;            // 0..15
    const int innr = (tid & 31) << 3;     // short offset in row, 16B chunks
    #pragma unroll
    for (int tap = 0; tap < 3; ++tap){
      const int gbase = b*HROWS + PAD + tile*64 + (tap-1)*dil;
      #pragma unroll
      for (int ch = 0; ch < 4; ++ch){
        int r = ch*16 + rsub;
        u4 v = *(const u4*)(hSrc + (size_t)(gbase + r)*NCH + innr);
        *(u4*)(Ht + tap*16384 + r*NCH + (innr ^ ((r & 7) << 3))) = v;
      }
    }
  }
  __syncthreads();

  // ---- phase 1: dilated conv as 24 pipelined K-steps ----
  LB1(0, 0);
  #pragma unroll
  for (int s = 0; s < 24; ++s){
    const int cur = s & 1, nxt = cur ^ 1;
    if (s < 23){ LA1(s+1, nxt); LB1(s+1, nxt); }
    #pragma unroll
    for (int mf = 0; mf < 4; ++mf)
      #pragma unroll
      for (int nf = 0; nf < 4; ++nf)
        acc[mf][nf] = MFMA(Ap[cur][mf], Bp[cur][nf], acc[mf][nf]);
  }

  // ---- hoisted gate operands (coalesced; independent of LDS) ----
  s4v cvf[4][4];
  {
    const short* cbase = condl + (((size_t)tile*8 + w)*16)*256 + lane*4;
    #pragma unroll
    for (int mf = 0; mf < 4; ++mf)
      #pragma unroll
      for (int nf = 0; nf < 4; ++nf)
        cvf[mf][nf] = *(const s4v*)(cbase + (mf*4 + nf)*256);
  }
  float bias[4][4];
  #pragma unroll
  for (int mf = 0; mf < 4; ++mf){
    f4 t = *(const f4*)(cb_l + b*4096 + orow + mf*16 + 4*g);
    #pragma unroll
    for (int j = 0; j < 4; ++j) bias[mf][j] = t[j];
  }
  float rbv[4][4];
  #pragma unroll
  for (int mf = 0; mf < 4; ++mf){
    f4 t = *(const f4*)(rsb_l + orow + mf*16 + 4*g);
    #pragma unroll
    for (int j = 0; j < 4; ++j) rbv[mf][j] = t[j];
  }

  // ---- gate: waves 4-7 write sigma(in_act_hi); waves 0-3 tanh*sigma in place ----
  if (w >= 4){
    #pragma unroll
    for (int mf = 0; mf < 4; ++mf){
      #pragma unroll
      for (int nf = 0; nf < 4; ++nf){
        int tl = nf*16 + l15;
        s4v pk;
        #pragma unroll
        for (int j = 0; j < 4; ++j){
          float x = acc[mf][nf][j] + bias[mf][j] + b2f(cvf[mf][nf][j]);
          x = fminf(fmaxf(x, -30.f), 30.f);
          pk[j] = f2b(1.f/(1.f + __expf(-x)));
        }
        int cb0 = (orow - NCH) + mf*16 + 4*g;
        *(s4v*)(xb + tl*NCH + (cb0 ^ sw8)) = pk;
      }
    }
  }
  __syncthreads();
  if (w < 4){
    #pragma unroll
    for (int mf = 0; mf < 4; ++mf){
      #pragma unroll
      for (int nf = 0; nf < 4; ++nf){
        int tl = nf*16 + l15;
        int cb0 = orow + mf*16 + 4*g;
        short* p = xb + tl*NCH + (cb0 ^ sw8);
        s4v sg = *(const s4v*)p;
        s4v pk;
        #pragma unroll
        for (int j = 0; j < 4; ++j){
          float x = acc[mf][nf][j] + bias[mf][j] + b2f(cvf[mf][nf][j]);
          x = fminf(fmaxf(x, -30.f), 30.f);
          float e = __expf(2.f*x);
          float th = (e - 1.f)/(e + 1.f);
          pk[j] = f2b(th * b2f(sg[j]));
        }
        *(s4v*)p = pk;
      }
    }
  }
  LA2(0, 0);          // prefetch phase-2 weights across the barrier
  __syncthreads();

  // ---- phase 2: res/skip 1x1 GEMM, 8 pipelined K-steps ----
  #pragma unroll
  for (int mf = 0; mf < 4; ++mf)
    #pragma unroll
    for (int nf = 0; nf < 4; ++nf) acc[mf][nf] = (f4){0.f,0.f,0.f,0.f};
  LB2(0, 0);
  #pragma unroll
  for (int s = 0; s < 8; ++s){
    const int cur = s & 1, nxt = cur ^ 1;
    if (s < 7){ LA2(s+1, nxt); LB2(s+1, nxt); }
    #pragma unroll
    for (int mf = 0; mf < 4; ++mf)
      #pragma unroll
      for (int nf = 0; nf < 4; ++nf)
        acc[mf][nf] = MFMA(Ap[cur][mf], Bp[cur][nf], acc[mf][nf]);
  }

  // ---- epilogue: h += rs[:256] (scattered stores) ; outF += rs[256:] (coalesced RMW) ----
  if (w < 4){
    #pragma unroll
    for (int mf = 0; mf < 4; ++mf){
      #pragma unroll
      for (int nf = 0; nf < 4; ++nf){
        int tl = nf*16 + l15;
        int cb0 = orow + mf*16 + 4*g;
        s4v hold = *(const s4v*)(Ht + 16384 + tl*NCH + (cb0 ^ sw8));  // center tap = h_old
        s4v pk;
        #pragma unroll
        for (int j = 0; j < 4; ++j)
          pk[j] = f2b(b2f(hold[j]) + acc[mf][nf][j] + rbv[mf][j]);
        *(s4v*)(hDst + ((size_t)b*HROWS + PAD + tile*64 + tl)*NCH + cb0) = pk;
      }
    }
  } else {
    short* obase = outF + (((size_t)(b*64 + tile)*4 + (w-4))*16)*256 + lane*4;
    #pragma unroll
    for (int mf = 0; mf < 4; ++mf){
      #pragma unroll
      for (int nf = 0; nf < 4; ++nf){
        short* op = obase + (mf*4 + nf)*256;
        s4v prev = *(const s4v*)op;
        s4v pk;
        #pragma unroll
        for (int j = 0; j < 4; ++j)
          pk[j] = f2b(b2f(prev[j]) + acc[mf][nf][j] + rbv[mf][j]);
        *(s4v*)op = pk;
      }
    }
  }
#undef LA1
#undef LB1
#undef LA2
#undef LB2
}

// ---------------- final: y = end_w @ skip + end_b (fragment-ordered outF) ----------------
__global__ void final_k(const short* __restrict__ outF, const float* __restrict__ end_w,
                        const float* __restrict__ end_b, float* __restrict__ y){
  __shared__ float ew[16*NCH];
  __shared__ float eb[16];
  int b = blockIdx.y, tile = blockIdx.x;
  for (int i = threadIdx.x; i < 16*NCH; i += 256) ew[i] = end_w[i];
  if (threadIdx.x < 16) eb[threadIdx.x] = end_b[threadIdx.x];
  __syncthreads();
  int r = threadIdx.x & 63, og = threadIdx.x >> 6;
  int nf = r >> 4, l15 = r & 15;
  const short* base = outF + (((size_t)(b*64 + tile)*4)*16)*256;
  float acc[4];
  #pragma unroll
  for (int j = 0; j < 4; ++j) acc[j] = eb[og*4 + j];
  #pragma unroll
  for (int w4 = 0; w4 < 4; ++w4){
    #pragma unroll
    for (int mf = 0; mf < 4; ++mf){
      #pragma unroll
      for (int q = 0; q < 4; ++q){
        s4v v = *(const s4v*)(base + (w4*16 + mf*4 + nf)*256 + (q*16 + l15)*4);
        int c = w4*64 + mf*16 + q*4;
        #pragma unroll
        for (int j = 0; j < 4; ++j){
          float f = b2f(v[j]);
          #pragma unroll
          for (int o4 = 0; o4 < 4; ++o4) acc[o4] += f * ew[(og*4 + o4)*NCH + c + j];
        }
      }
    }
  }
  int t = tile*64 + r;
  #pragma unroll
  for (int j = 0; j < 4; ++j){
    int o = og*4 + j;
    float* dst = (o < 8) ? (y + ((size_t)(b*8 + o))*T_LEN)
                         : (y + 131072 + ((size_t)(b*8 + o - 8))*T_LEN);
    dst[t] = acc[j];
  }
}

extern "C" void kernel_launch(void* const* d_in, const int* in_sizes, int n_in,
                              void* d_out, int out_size, void* d_ws, size_t ws_size,
                              hipStream_t stream){
  const float* audio      = (const float*)d_in[0];
  const float* spect      = (const float*)d_in[1];
  const int*   pos        = (const int*)  d_in[2];
  const float* start_w    = (const float*)d_in[3];
  const float* start_b    = (const float*)d_in[4];
  const float* cond_w     = (const float*)d_in[5];
  const float* cond_b     = (const float*)d_in[6];
  const float* pos_emb_w  = (const float*)d_in[7];
  const float* pos_lin_w  = (const float*)d_in[8];
  const float* pos_lin_b  = (const float*)d_in[9];
  const float* in_w       = (const float*)d_in[10];
  const float* in_b       = (const float*)d_in[11];
  const float* rs_w       = (const float*)d_in[12];
  const float* rs_b       = (const float*)d_in[13];
  const float* rs_last_w  = (const float*)d_in[14];
  const float* rs_last_b  = (const float*)d_in[15];
  const float* end_w      = (const float*)d_in[16];
  const float* end_b      = (const float*)d_in[17];
  float* y = (float*)d_out;

  char* ws = (char*)d_ws;
  size_t off = 0;
  auto alloc = [&](size_t bytes) -> void* {
    void* p = ws + off;
    off += (bytes + 255) & ~(size_t)255;
    return p;
  };
  const size_t hBytes   = (size_t)BG*HROWS*NCH*2;     // 8,912,896
  const size_t condBy   = (size_t)4096*T_LEN*2;       // 33,554,432 (fragment-ordered)
  const size_t outBy    = (size_t)BG*T_LEN*NCH*2;     // 8,388,608  (fragment-ordered)
  short* hA     = (short*)alloc(hBytes);
  short* hB     = (short*)alloc(hBytes);
  short* cond   = (short*)alloc(condBy);
  short* outb   = (short*)alloc(outBy);
  short* W1     = (short*)alloc((size_t)NL*3*M2*NCH*2);
  short* W2     = (short*)alloc((size_t)NL*M2*NCH*2);
  float* rsb8   = (float*)alloc((size_t)NL*M2*4);
  float* cb     = (float*)alloc((size_t)BG*4096*4);
  short* Wc     = (short*)alloc((size_t)4096*128*2);
  short* spectT = (short*)alloc((size_t)4096*128*2);
  if (off > ws_size) return;  // insufficient workspace -> output stays zero (diagnosable)

  hipMemsetAsync(hA, 0, hBytes, stream);
  hipMemsetAsync(hB, 0, hBytes, stream);
  hipMemsetAsync(outb, 0, outBy, stream);

  prep_w <<<4096, 256, 0, stream>>>(in_w, rs_w, rs_last_w, rs_b, rs_last_b, cond_w,
                                    W1, W2, rsb8, Wc);
  prep_spectT<<<dim3(64, 2), 256, 0, stream>>>(spect, spectT);
  prep_cb<<<dim3(16, BG), 256, 0, stream>>>(pos, pos_emb_w, pos_lin_w, pos_lin_b, in_b, cb);
  prep_h0<<<dim3(64, BG), 256, 0, stream>>>(audio, start_w, start_b, hA);
  cond_gemm<<<dim3(64, 8), 512, 0, stream>>>(Wc, spectT, cond_b, cond);

  for (int l = 0; l < NL; ++l){
    const short* hS = (l & 1) ? hB : hA;
    short*       hD = (l & 1) ? hA : hB;
    wn_layer<<<dim3(64, BG), 512, 0, stream>>>(
        hS, hD,
        W1 + (size_t)l*3*M2*NCH,
        W2 + (size_t)l*M2*NCH,
        cond + (size_t)l*64*8*16*256,
        cb + l*M2,
        rsb8 + l*M2,
        outb, 1 << l);
  }
  final_k<<<dim3(64, BG), 256, 0, stream>>>(outb, end_w, end_b, y);
}